// Round 12
// baseline (370.667 us; speedup 1.0000x reference)
//
#include <hip/hip_runtime.h>
#include <stdint.h>

#define HID 256
#define NMAXPIX (1025 * 1025)
#define NREP 8     // histogram replicas (stages 3-4), replica-major
#define NSEG 2048  // selection segments (one wave each; 512 blocks)
#define SELMAX 2112

// per-stage small-buffer layout (u32 units) — R8 layout, stages 3-4 only
#define HISTA_OFF 0          // 8 x 2048
#define HISTB_OFF 16384      // 8 x 2048
#define HISTC_OFF 32768      // 8 x 1024
#define SCAL_OFF  40960      // [0]=pfx1 [1]=rem1 [2]=pfx2 [3]=rem2 [4]=K [5]=t (pad 64)
#define TIC_OFF   41024      // 2048
#define STAGE_U32 43072

// ---------------- MLP eval (single point), float4 LDS weight reads ----------------
__device__ __forceinline__ float mlp_eval4(float wx, float wy,
                                           const float4* __restrict__ w1x,
                                           const float4* __restrict__ w1y,
                                           const float4* __restrict__ vb1,
                                           const float4* __restrict__ vw2, float b2v) {
    const float C0 = (float)(0.5 / 1025.0);
    float px = (wx / 1025.0f + C0) * 2.0f - 1.0f;
    float py = (wy / 1025.0f + C0) * 2.0f - 1.0f;
    float a0 = 0.f, a1 = 0.f, a2 = 0.f, a3 = 0.f;
#pragma unroll 8
    for (int q = 0; q < HID / 4; ++q) {
        float4 a = w1x[q], b = w1y[q], c = vb1[q], d = vw2[q];
        float h0 = px * a.x + py * b.x + c.x;
        float h1 = px * a.y + py * b.y + c.y;
        float h2 = px * a.z + py * b.z + c.z;
        float h3 = px * a.w + py * b.w + c.w;
        h0 = h0 > 0.f ? h0 : 0.f;
        h1 = h1 > 0.f ? h1 : 0.f;
        h2 = h2 > 0.f ? h2 : 0.f;
        h3 = h3 > 0.f ? h3 : 0.f;
        a0 += h0 * d.x;
        a1 += h1 * d.y;
        a2 += h2 * d.z;
        a3 += h3 * d.w;
    }
    float x = ((a0 + a1) + (a2 + a3)) + b2v;
    float r;
    if (x >= 0.f) { r = 1.0f / (1.0f + expf(-x)); }
    else { float e = expf(x); r = e / (1.0f + e); }
    return r;
}

// ---------------- upsample value (bitwise dyadic averages) ----------------
__device__ __forceinline__ float upsample_val(const float* __restrict__ in, int rp, int r, int n) {
    int i = n / r, j = n % r;
    int i2 = i >> 1, j2 = j >> 1;
    float v;
    if ((i & 1) == 0) {
        if ((j & 1) == 0) {
            v = in[i2 * rp + j2];
        } else {
            float a = in[i2 * rp + j2], b = in[i2 * rp + j2 + 1];
            v = a * 0.5f + b * 0.5f;
        }
    } else {
        if ((j & 1) == 0) {
            float a = in[i2 * rp + j2], b = in[(i2 + 1) * rp + j2];
            v = a * 0.5f + b * 0.5f;
        } else {
            float a = in[i2 * rp + j2],      c = in[i2 * rp + j2 + 1];
            float b = in[(i2 + 1) * rp + j2], d = in[(i2 + 1) * rp + j2 + 1];
            float t1 = a * 0.5f + b * 0.5f;
            float t2 = c * 0.5f + d * 0.5f;
            v = t1 * 0.5f + t2 * 0.5f;
        }
    }
    return v;
}

__device__ __forceinline__ uint32_t key_of(float v) {
    float unc = -fabsf(v - 0.5f);
    uint32_t u = __float_as_uint(unc);
    return (u & 0x80000000u) ? ~u : (u | 0x80000000u);
}

// ---------------- block exclusive scan helper (256 threads) ----------------
__device__ __forceinline__ uint32_t block_exscan_256(uint32_t v, volatile uint32_t* lds4) {
    int lane = threadIdx.x & 63, w = threadIdx.x >> 6;
    uint32_t inc = v;
#pragma unroll
    for (int d = 1; d < 64; d <<= 1) {
        uint32_t o = (uint32_t)__shfl_up((int)inc, d, 64);
        if (lane >= d) inc += o;
    }
    if (lane == 63) lds4[w] = inc;
    __syncthreads();
    uint32_t woff = 0;
    for (int i = 0; i < w; ++i) woff += lds4[i];
    return woff + inc - v;
}

// ---------------- block exclusive scan helper (1024 threads, 16 waves) ----------------
__device__ __forceinline__ uint32_t block_exscan_1024(uint32_t v, volatile uint32_t* lds16) {
    int lane = threadIdx.x & 63, w = threadIdx.x >> 6;
    uint32_t inc = v;
#pragma unroll
    for (int d = 1; d < 64; d <<= 1) {
        uint32_t o = (uint32_t)__shfl_up((int)inc, d, 64);
        if (lane >= d) inc += o;
    }
    if (lane == 63) lds16[w] = inc;
    __syncthreads();
    uint32_t woff = 0;
    for (int i = 0; i < w; ++i) woff += lds16[i];
    return woff + inc - v;
}

// ---------------- redundant per-block radix scan of a replicated global histogram (256 thr) ----
__device__ void scan_dev(const uint32_t* __restrict__ hist, int NB,
                         uint32_t rem_in, uint32_t prefix_in, int shift,
                         uint32_t* outp, uint32_t* outr,
                         volatile uint32_t* lds4, volatile uint32_t* ldspair) {
    int tid = threadIdx.x;
    int C = NB >> 8;
    int b0 = NB - (tid + 1) * C;
    uint32_t cnts[8];
#pragma unroll
    for (int k = 0; k < 8; ++k) cnts[k] = 0;
    for (int rep = 0; rep < NREP; ++rep) {
        const uint4* p = (const uint4*)(hist + (size_t)rep * NB + b0);
#pragma unroll
        for (int g = 0; g < 2; ++g) {
            if (g * 4 < C) {
                uint4 v = p[g];
                cnts[g * 4 + 0] += v.x;
                cnts[g * 4 + 1] += v.y;
                cnts[g * 4 + 2] += v.z;
                cnts[g * 4 + 3] += v.w;
            }
        }
    }
    uint32_t ssum = 0;
    for (int k = 0; k < C; ++k) ssum += cnts[k];
    uint32_t excl = block_exscan_256(ssum, lds4);
    uint32_t run = excl;
    for (int k = 0; k < C; ++k) {
        uint32_t c = cnts[C - 1 - k];
        if (rem_in > run && rem_in <= run + c) {
            ldspair[0] = (prefix_in << shift) | (uint32_t)(b0 + C - 1 - k);
            ldspair[1] = rem_in - run;
        }
        run += c;
    }
    __syncthreads();
    *outp = ldspair[0];
    *outr = ldspair[1];
}

// ---------------- LDS-histogram radix scan (1024 threads, in-block) ----------------
__device__ void scan_lds(const uint32_t* hist, int NB,
                         uint32_t rem_in, uint32_t prefix_in, int shift,
                         uint32_t* outp, uint32_t* outr,
                         volatile uint32_t* lds16, volatile uint32_t* ldspair) {
    int tid = threadIdx.x;
    int C = NB >> 10;               // 2 (NB=2048) or 1 (NB=1024)
    int b0 = NB - (tid + 1) * C;    // thread 0 owns top bins
    uint32_t c0 = hist[b0];
    uint32_t c1 = (C == 2) ? hist[b0 + 1] : 0u;
    uint32_t ssum = c0 + c1;
    uint32_t excl = block_exscan_1024(ssum, lds16);  // internal sync: all hist reads done before
    uint32_t run = excl;
    // descending bin order within thread
    if (C == 2) {
        if (rem_in > run && rem_in <= run + c1) {
            ldspair[0] = (prefix_in << shift) | (uint32_t)(b0 + 1);
            ldspair[1] = rem_in - run;
        }
        run += c1;
    }
    if (rem_in > run && rem_in <= run + c0) {
        ldspair[0] = (prefix_in << shift) | (uint32_t)b0;
        ldspair[1] = rem_in - run;
    }
    __syncthreads();
    *outp = ldspair[0];
    *outr = ldspair[1];
}

// ---------------- wave-aggregated LDS histogram add ----------------
__device__ __forceinline__ void lds_hist_add(uint32_t* hist, bool act, uint32_t bin, int lane) {
    unsigned long long m = __ballot(act);
    if (m) {
        int leader = __ffsll(m) - 1;
        uint32_t lbin = (uint32_t)__shfl((int)bin, leader, 64);
        unsigned long long smk = __ballot(act && bin == lbin);
        if (smk == m) {
            if (lane == leader) atomicAdd(&hist[lbin], (uint32_t)__popcll(m));
        } else if (act) {
            atomicAdd(&hist[bin], 1u);
        }
    }
}

// ---------------- eval0 + zero all per-stage buffers ----------------
__global__ __launch_bounds__(256) void k_eval0z(const float* __restrict__ w1, const float* __restrict__ b1,
                                                const float* __restrict__ w2, const float* __restrict__ b2,
                                                float* __restrict__ occ, uint32_t* __restrict__ zbuf, int zcount) {
    __shared__ alignas(16) float sw1[2 * HID];
    __shared__ alignas(16) float sb1[HID];
    __shared__ alignas(16) float sw2[HID];
    int tid = threadIdx.x;
    for (int i = tid; i < 2 * HID; i += 256) sw1[i] = w1[i];
    sb1[tid] = b1[tid];
    sw2[tid] = w2[tid];
    __syncthreads();
    int gtid = blockIdx.x * 256 + tid;
    int nthreads = gridDim.x * 256;
    for (int i = gtid; i < zcount; i += nthreads) zbuf[i] = 0;
    for (int n = gtid; n < 65 * 65; n += nthreads) {
        int i = n / 65, j = n % 65;
        occ[n] = mlp_eval4(16.0f * (float)j, 16.0f * (float)i,
                           (const float4*)sw1, (const float4*)(sw1 + HID),
                           (const float4*)sb1, (const float4*)sw2, b2[0]);
    }
}

// ---------------- SMALL STAGE: one 1024-thread block does upsample+keys+full radix+tie select ----
__global__ __launch_bounds__(1024) void k_small(const float* __restrict__ in, int rp,
                                                float* __restrict__ outg, int r, uint32_t npt,
                                                uint32_t* __restrict__ keys,
                                                uint32_t* __restrict__ list) {
    __shared__ uint32_t hist[2048];
    __shared__ uint32_t lds16[16];
    __shared__ uint32_t ldspair[2];
    __shared__ uint32_t iterw[16], itert[16];
    int tid = threadIdx.x, lane = tid & 63, w = tid >> 6;
    int N = r * r;
    for (int k = tid; k < 2048; k += 1024) hist[k] = 0;
    __syncthreads();

    // phase A: upsample + key write + msb-11 LDS histogram
    for (int n0 = 0; n0 < N; n0 += 1024) {
        int n = n0 + tid;
        bool act = n < N;
        uint32_t key = 0;
        if (act) {
            float v = upsample_val(in, rp, r, n);
            outg[n] = v;
            key = key_of(v);
            keys[n] = key;
        }
        lds_hist_add(hist, act, key >> 21, lane);
    }
    __syncthreads();
    uint32_t pfx, rem;
    scan_lds(hist, 2048, npt, 0u, 0, &pfx, &rem, lds16, ldspair);
    __syncthreads();

    // phase B: filtered mid-11 histogram
    for (int k = tid; k < 2048; k += 1024) hist[k] = 0;
    __syncthreads();
    for (int n0 = 0; n0 < N; n0 += 1024) {
        int n = n0 + tid;
        bool inb = n < N;
        uint32_t key = inb ? keys[n] : 0u;
        bool flt = inb && ((key >> 21) == pfx);
        lds_hist_add(hist, flt, (key >> 10) & 0x7FFu, lane);
    }
    __syncthreads();
    scan_lds(hist, 2048, rem, pfx, 11, &pfx, &rem, lds16, ldspair);
    __syncthreads();

    // phase C: filtered low-10 histogram
    for (int k = tid; k < 1024; k += 1024) hist[k] = 0;
    __syncthreads();
    for (int n0 = 0; n0 < N; n0 += 1024) {
        int n = n0 + tid;
        bool inb = n < N;
        uint32_t key = inb ? keys[n] : 0u;
        bool flt = inb && ((key >> 10) == pfx);
        lds_hist_add(hist, flt, key & 0x3FFu, lane);
    }
    __syncthreads();
    uint32_t K, t;
    scan_lds(hist, 1024, rem, pfx, 10, &K, &t, lds16, ldspair);
    __syncthreads();

    // select: exact top-k, index-ascending ties. Chunks of 4096; wave w owns [base+256w, +256).
    unsigned long long lowmask = (lane == 63) ? ~0ull >> 1 : ((1ull << lane) - 1ull);
    uint32_t running_sel = 0, running_tie = 0;
    for (int base = 0; base < N; base += 4096) {
        int nb0 = base + w * 256;
        uint32_t kq[4];
        unsigned long long tmq[4], smq[4];
        uint32_t wtie = 0;
        // S0: ballots of ties (index order: q ascending, lanes ascending)
#pragma unroll
        for (int q = 0; q < 4; ++q) {
            int n = nb0 + q * 64 + lane;
            bool inb = n < N;
            kq[q] = inb ? keys[n] : 0u;
            bool tie = inb && (kq[q] == K);
            tmq[q] = __ballot(tie);
            wtie += (uint32_t)__popcll(tmq[q]);
        }
        if (lane == 0) itert[w] = wtie;
        __syncthreads();
        // S1: ranks -> sel ballots
        uint32_t wtp = running_tie;
        for (int ww = 0; ww < w; ++ww) wtp += itert[ww];
        uint32_t wsel = 0;
#pragma unroll
        for (int q = 0; q < 4; ++q) {
            int n = nb0 + q * 64 + lane;
            bool inb = n < N;
            bool gt = inb && (kq[q] > K);
            bool tie = inb && (kq[q] == K);
            uint32_t trank = wtp + (uint32_t)__popcll(tmq[q] & lowmask);
            bool sel = gt || (tie && trank < t);
            smq[q] = __ballot(sel);
            wtp += (uint32_t)__popcll(tmq[q]);
            wsel += (uint32_t)__popcll(smq[q]);
        }
        if (lane == 0) iterw[w] = wsel;
        __syncthreads();
        // S2: write selected indices at exact positions
        uint32_t wsp = running_sel;
        for (int ww = 0; ww < w; ++ww) wsp += iterw[ww];
#pragma unroll
        for (int q = 0; q < 4; ++q) {
            int n = nb0 + q * 64 + lane;
            bool sel = (smq[q] >> lane) & 1ull;
            if (sel) list[wsp + (uint32_t)__popcll(smq[q] & lowmask)] = (uint32_t)n;
            wsp += (uint32_t)__popcll(smq[q]);
        }
        // all threads update running sums identically (registers)
        for (int ww = 0; ww < 16; ++ww) { running_sel += iterw[ww]; running_tie += itert[ww]; }
        __syncthreads();
    }
}

// ---------------- dense eval of compacted list: 4 points per thread (grid-wide) ----------------
__global__ __launch_bounds__(256) void k_evalpts(const uint32_t* __restrict__ outlist, int r, float stride,
                                                 float* __restrict__ occ,
                                                 const float* __restrict__ w1, const float* __restrict__ b1,
                                                 const float* __restrict__ w2, const float* __restrict__ b2) {
    __shared__ alignas(16) float sw1[2 * HID];
    __shared__ alignas(16) float sb1[HID];
    __shared__ alignas(16) float sw2[HID];
    int tid = threadIdx.x;
    for (int i = tid; i < 2 * HID; i += 256) sw1[i] = w1[i];
    sb1[tid] = b1[tid];
    sw2[tid] = w2[tid];
    __syncthreads();
    const float4* w1x = (const float4*)sw1;
    const float4* w1y = (const float4*)(sw1 + HID);
    const float4* vb1 = (const float4*)sb1;
    const float4* vw2 = (const float4*)sw2;
    float vb2 = b2[0];
    const float C0 = (float)(0.5 / 1025.0);
    int gid = blockIdx.x * 256 + tid;
    uint4 nn = ((const uint4*)outlist)[gid];   // npt multiple of 1024 -> no tail
    uint32_t n0 = nn.x, n1 = nn.y, n2 = nn.z, n3 = nn.w;
    float px0, py0, px1, py1, px2, py2, px3, py3;
    {
        int i0 = (int)n0 / r, j0 = (int)n0 % r;
        int i1 = (int)n1 / r, j1 = (int)n1 % r;
        int i2 = (int)n2 / r, j2 = (int)n2 % r;
        int i3 = (int)n3 / r, j3 = (int)n3 % r;
        px0 = ((stride * (float)j0) / 1025.0f + C0) * 2.0f - 1.0f;
        py0 = ((stride * (float)i0) / 1025.0f + C0) * 2.0f - 1.0f;
        px1 = ((stride * (float)j1) / 1025.0f + C0) * 2.0f - 1.0f;
        py1 = ((stride * (float)i1) / 1025.0f + C0) * 2.0f - 1.0f;
        px2 = ((stride * (float)j2) / 1025.0f + C0) * 2.0f - 1.0f;
        py2 = ((stride * (float)i2) / 1025.0f + C0) * 2.0f - 1.0f;
        px3 = ((stride * (float)j3) / 1025.0f + C0) * 2.0f - 1.0f;
        py3 = ((stride * (float)i3) / 1025.0f + C0) * 2.0f - 1.0f;
    }
    float4 A0 = {0, 0, 0, 0}, A1 = {0, 0, 0, 0}, A2 = {0, 0, 0, 0}, A3 = {0, 0, 0, 0};
#pragma unroll 4
    for (int q = 0; q < HID / 4; ++q) {
        float4 a = w1x[q], b = w1y[q], c = vb1[q], d = vw2[q];
#define STEP(P, AX) {                                              \
        float h0 = px##P * a.x + py##P * b.x + c.x;                \
        float h1 = px##P * a.y + py##P * b.y + c.y;                \
        float h2 = px##P * a.z + py##P * b.z + c.z;                \
        float h3 = px##P * a.w + py##P * b.w + c.w;                \
        h0 = h0 > 0.f ? h0 : 0.f;                                  \
        h1 = h1 > 0.f ? h1 : 0.f;                                  \
        h2 = h2 > 0.f ? h2 : 0.f;                                  \
        h3 = h3 > 0.f ? h3 : 0.f;                                  \
        AX.x += h0 * d.x; AX.y += h1 * d.y;                        \
        AX.z += h2 * d.z; AX.w += h3 * d.w; }
        STEP(0, A0) STEP(1, A1) STEP(2, A2) STEP(3, A3)
#undef STEP
    }
#define FIN(AX, NP) {                                              \
        float x = ((AX.x + AX.y) + (AX.z + AX.w)) + vb2;           \
        float rr;                                                  \
        if (x >= 0.f) { rr = 1.0f / (1.0f + expf(-x)); }           \
        else { float e = expf(x); rr = e / (1.0f + e); }           \
        occ[NP] = rr; }
    FIN(A0, n0) FIN(A1, n1) FIN(A2, n2) FIN(A3, n3)
#undef FIN
}

// ---------------- R8 pipeline kernels for stages 3-4 ----------------
__global__ __launch_bounds__(256) void k_upkey(const float* __restrict__ in, int rp,
                                               float* __restrict__ outg, int r, int nb, int bstride,
                                               uint32_t* __restrict__ keys,
                                               uint32_t* __restrict__ histA) {
    __shared__ uint32_t hist[2048];
    int tid = threadIdx.x;
    for (int k = tid; k < 2048; k += 256) hist[k] = 0;
    __syncthreads();
    int N = r * r;
    int lane = tid & 63;
    int gstride = gridDim.x * 256;
    for (int n0 = blockIdx.x * 256; n0 < N; n0 += gstride) {
        int n = n0 + tid;
        bool act = n < N;
        uint32_t key = 0;
        if (act) {
            float v = upsample_val(in, rp, r, n);
            for (int k = 0; k < nb; ++k) outg[(size_t)k * bstride + n] = v;
            key = key_of(v);
            keys[n] = key;
        }
        lds_hist_add(hist, act, key >> 21, lane);
    }
    __syncthreads();
    uint32_t* myrep = histA + (size_t)(blockIdx.x & (NREP - 1)) * 2048;
    for (int k = tid; k < 2048; k += 256) {
        uint32_t c = hist[k];
        if (c) atomicAdd(&myrep[k], c);
    }
}

__global__ __launch_bounds__(256) void k_histmid(const uint32_t* __restrict__ keys, int N,
                                                 const uint32_t* __restrict__ prevHist,
                                                 uint32_t* __restrict__ scal,
                                                 int useNpt, uint32_t npt, int scalInIdx, int shift,
                                                 int scalOutIdx,
                                                 int fshift, int bshift, uint32_t bmask,
                                                 uint32_t* __restrict__ outHist, int NBout) {
    __shared__ uint32_t lh[2048];
    __shared__ uint32_t lds4[4];
    __shared__ uint32_t ldspair[2];
    int tid = threadIdx.x, lane = tid & 63;
    uint32_t rem_in = useNpt ? npt : scal[scalInIdx + 1];
    uint32_t pfx_in = useNpt ? 0u  : scal[scalInIdx];
    uint32_t pfx, rem;
    scan_dev(prevHist, 2048, rem_in, pfx_in, shift, &pfx, &rem, lds4, ldspair);
    if (blockIdx.x == 0 && tid == 0) { scal[scalOutIdx] = pfx; scal[scalOutIdx + 1] = rem; }
    for (int k = tid; k < 2048; k += 256) lh[k] = 0;
    __syncthreads();
    int gstride = gridDim.x * 256;
    for (int base = blockIdx.x * 256; base < N; base += gstride) {
        int n = base + tid;
        bool inb = n < N;
        uint32_t key = inb ? keys[n] : 0u;
        bool flt = inb && ((key >> fshift) == pfx);
        lds_hist_add(lh, flt, (key >> bshift) & bmask, lane);
    }
    __syncthreads();
    uint32_t* myrep = outHist + (size_t)(blockIdx.x & (NREP - 1)) * NBout;
    for (int k = tid; k < NBout; k += 256) {
        uint32_t c = lh[k];
        if (c) atomicAdd(&myrep[k], c);
    }
}

__global__ __launch_bounds__(256) void k_segcnt(const uint32_t* __restrict__ keys, int N, int seglen,
                                                const uint32_t* __restrict__ histC,
                                                uint32_t* __restrict__ scal,
                                                uint32_t* __restrict__ tic) {
    __shared__ uint32_t lds4[4];
    __shared__ uint32_t ldspair[2];
    int tid = threadIdx.x, lane = tid & 63;
    uint32_t rem2 = scal[3], pfx2 = scal[2];
    uint32_t K, t;
    scan_dev(histC, 1024, rem2, pfx2, 10, &K, &t, lds4, ldspair);
    if (blockIdx.x == 0 && tid == 0) { scal[4] = K; scal[5] = t; }
    int wv = blockIdx.x * 4 + (tid >> 6);
    int s0 = wv * seglen;
    int s1 = s0 + seglen; if (s1 > N) s1 = N;
    uint32_t tcnt = 0;
    for (int base = s0; base < s1; base += 64) {
        int n = base + lane;
        if (n < s1) tcnt += (keys[n] == K) ? 1u : 0u;
    }
#pragma unroll
    for (int d = 32; d; d >>= 1) tcnt += (uint32_t)__shfl_down((int)tcnt, d, 64);
    if (lane == 0) tic[wv] = tcnt;
}

__global__ __launch_bounds__(256) void k_seleval(const uint32_t* __restrict__ keys, int N, int seglen,
                                                 const uint32_t* __restrict__ scal,
                                                 const uint32_t* __restrict__ tic,
                                                 int r, float stride,
                                                 float* __restrict__ occ, int nb, int bstride,
                                                 const float* __restrict__ w1, const float* __restrict__ b1,
                                                 const float* __restrict__ w2, const float* __restrict__ b2) {
    __shared__ alignas(16) float sw1[2 * HID];
    __shared__ alignas(16) float sb1[HID];
    __shared__ alignas(16) float sw2[HID];
    __shared__ uint32_t selcnt;
    __shared__ uint32_t selidx[SELMAX];
    int tid = threadIdx.x, lane = tid & 63;
    for (int i = tid; i < 2 * HID; i += 256) sw1[i] = w1[i];
    sb1[tid] = b1[tid];
    sw2[tid] = w2[tid];
    if (tid == 0) selcnt = 0;
    __syncthreads();
    uint32_t K = scal[4], t = scal[5];

    int wv = blockIdx.x * 4 + (tid >> 6);
    uint32_t tp = 0;
    for (int i = lane; i < wv; i += 64) tp += tic[i];
#pragma unroll
    for (int d = 32; d; d >>= 1) tp += (uint32_t)__shfl_down((int)tp, d, 64);
    tp = (uint32_t)__shfl((int)tp, 0, 64);

    uint32_t tie_run = tp;
    int s0 = wv * seglen;
    int s1 = s0 + seglen; if (s1 > N) s1 = N;
    unsigned long long lowmask = (lane == 63) ? ~0ull >> 1 : ((1ull << lane) - 1ull);
    for (int base = s0; base < s1; base += 64) {
        int n = base + lane;
        bool inb = n < s1;
        uint32_t key = inb ? keys[n] : 0u;
        bool gt = inb && (key > K);
        bool tie = inb && (key == K);
        unsigned long long tm = __ballot(tie);
        uint32_t trank = tie_run + (uint32_t)__popcll(tm & lowmask);
        bool sel = gt || (tie && trank < t);
        unsigned long long smk = __ballot(sel);
        if (smk) {
            int leader = __ffsll(smk) - 1;
            uint32_t wbase = 0;
            if (lane == leader) wbase = atomicAdd(&selcnt, (uint32_t)__popcll(smk));
            wbase = (uint32_t)__shfl((int)wbase, leader, 64);
            if (sel) selidx[wbase + (uint32_t)__popcll(smk & lowmask)] = (uint32_t)n;
        }
        tie_run += (uint32_t)__popcll(tm);
    }
    __syncthreads();

    uint32_t cnt = selcnt;
    float vb2 = b2[0];
    const float4* w1x = (const float4*)sw1;
    const float4* w1y = (const float4*)(sw1 + HID);
    const float4* vb1 = (const float4*)sb1;
    const float4* vw2 = (const float4*)sw2;
    const float C0 = (float)(0.5 / 1025.0);
    for (uint32_t bb = 0; bb < cnt; bb += 1024) {
        uint32_t i0 = bb + tid, i1 = i0 + 256, i2 = i0 + 512, i3 = i0 + 768;
        bool v0 = i0 < cnt, v1 = i1 < cnt, v2 = i2 < cnt, v3 = i3 < cnt;
        int nA = v0 ? (int)selidx[i0] : 0;
        int nB = v1 ? (int)selidx[i1] : 0;
        int nC = v2 ? (int)selidx[i2] : 0;
        int nD = v3 ? (int)selidx[i3] : 0;
        int iA = nA / r, jA = nA % r;
        int iB = nB / r, jB = nB % r;
        int iC = nC / r, jC = nC % r;
        int iD = nD / r, jD = nD % r;
        float px0 = ((stride * (float)jA) / 1025.0f + C0) * 2.0f - 1.0f;
        float py0 = ((stride * (float)iA) / 1025.0f + C0) * 2.0f - 1.0f;
        float px1 = ((stride * (float)jB) / 1025.0f + C0) * 2.0f - 1.0f;
        float py1 = ((stride * (float)iB) / 1025.0f + C0) * 2.0f - 1.0f;
        float px2 = ((stride * (float)jC) / 1025.0f + C0) * 2.0f - 1.0f;
        float py2 = ((stride * (float)iC) / 1025.0f + C0) * 2.0f - 1.0f;
        float px3 = ((stride * (float)jD) / 1025.0f + C0) * 2.0f - 1.0f;
        float py3 = ((stride * (float)iD) / 1025.0f + C0) * 2.0f - 1.0f;
        float4 A0 = {0, 0, 0, 0}, A1 = {0, 0, 0, 0}, A2 = {0, 0, 0, 0}, A3 = {0, 0, 0, 0};
#pragma unroll 4
        for (int q = 0; q < HID / 4; ++q) {
            float4 a = w1x[q], b = w1y[q], c = vb1[q], d = vw2[q];
#define STEP(P, AX) {                                              \
            float h0 = px##P * a.x + py##P * b.x + c.x;            \
            float h1 = px##P * a.y + py##P * b.y + c.y;            \
            float h2 = px##P * a.z + py##P * b.z + c.z;            \
            float h3 = px##P * a.w + py##P * b.w + c.w;            \
            h0 = h0 > 0.f ? h0 : 0.f;                              \
            h1 = h1 > 0.f ? h1 : 0.f;                              \
            h2 = h2 > 0.f ? h2 : 0.f;                              \
            h3 = h3 > 0.f ? h3 : 0.f;                              \
            AX.x += h0 * d.x; AX.y += h1 * d.y;                    \
            AX.z += h2 * d.z; AX.w += h3 * d.w; }
            STEP(0, A0) STEP(1, A1) STEP(2, A2) STEP(3, A3)
#undef STEP
        }
#define FIN(VQ, AX, NP) if (VQ) {                                  \
        float x = ((AX.x + AX.y) + (AX.z + AX.w)) + vb2;           \
        float rr;                                                  \
        if (x >= 0.f) { rr = 1.0f / (1.0f + expf(-x)); }           \
        else { float e = expf(x); rr = e / (1.0f + e); }           \
        for (int k = 0; k < nb; ++k) occ[(size_t)k * bstride + NP] = rr; }
        FIN(v0, A0, nA) FIN(v1, A1, nB) FIN(v2, A2, nC) FIN(v3, A3, nD)
#undef FIN
    }
}

// ---------------- fallback-only broadcast ----------------
__global__ __launch_bounds__(256) void k_bcast(const float* __restrict__ src, float* __restrict__ dst, int N) {
    int q = blockIdx.x * 256 + threadIdx.x;
    int n = q * 4;
    if (n + 3 < N) {
        float4 v = *(const float4*)(src + n);
#pragma unroll
        for (int k = 0; k < 8; ++k) *(float4*)(dst + (size_t)k * N + n) = v;
    } else if (n < N) {
        for (int m = n; m < N; ++m) {
            float v = src[m];
#pragma unroll
            for (int k = 0; k < 8; ++k) dst[(size_t)k * N + m] = v;
        }
    }
}

extern "C" void kernel_launch(void* const* d_in, const int* in_sizes, int n_in,
                              void* d_out, int out_size, void* d_ws, size_t ws_size,
                              hipStream_t stream) {
    const float* w1 = (const float*)d_in[0];
    const float* b1 = (const float*)d_in[1];
    const float* w2 = (const float*)d_in[2];
    const float* b2 = (const float*)d_in[3];
    float* out = (float*)d_out;

    const size_t A = (((size_t)NMAXPIX * 4) + 255) & ~(size_t)255;
    const size_t SMALL_BYTES = (size_t)4 * STAGE_U32 * 4;
    const size_t LIST_BYTES = (size_t)16384 * 4;
    const size_t need = 3 * A + SMALL_BYTES + LIST_BYTES;

    int fused8 = (ws_size >= need);
    char* base = fused8 ? (char*)d_ws : (char*)d_out;
    float* buf0 = (float*)(base);
    float* buf1 = (float*)(base + A);
    uint32_t* keys = (uint32_t*)(base + 2 * A);
    uint32_t* smallb = (uint32_t*)(base + 3 * A);
    uint32_t* list = (uint32_t*)(base + 3 * A + SMALL_BYTES);

    // dispatch 1: zero stage buffers + dense 65x65 eval
    k_eval0z<<<dim3(512), dim3(256), 0, stream>>>(w1, b1, w2, b2, buf0, smallb, 4 * STAGE_U32);

    // stage 1 (65->129, npt 4096): single-block select + grid-wide eval
    k_small<<<dim3(1), dim3(1024), 0, stream>>>(buf0, 65, buf1, 129, 4096u, keys, list);
    k_evalpts<<<dim3(4), dim3(256), 0, stream>>>(list, 129, 1024.0f / 128.0f, buf1, w1, b1, w2, b2);

    // stage 2 (129->257, npt 16384)
    k_small<<<dim3(1), dim3(1024), 0, stream>>>(buf1, 129, buf0, 257, 16384u, keys, list);
    k_evalpts<<<dim3(16), dim3(256), 0, stream>>>(list, 257, 1024.0f / 256.0f, buf0, w1, b1, w2, b2);

    // stages 3-4: R8 five-dispatch pipeline
    const int resA[5] = {65, 129, 257, 513, 1025};
    const int nptA[5] = {0, 4096, 16384, 65536, 262144};
    float* cur = buf0;   // holds 257^2 grid
    float* nxt = buf1;
    for (int s = 3; s < 5; ++s) {
        int rp = resA[s - 1], r = resA[s];
        int N = r * r;
        uint32_t npt = (uint32_t)nptA[s];
        uint32_t* sm = smallb + (size_t)(s - 1) * STAGE_U32;
        uint32_t* histA = sm + HISTA_OFF;
        uint32_t* histB = sm + HISTB_OFF;
        uint32_t* histC = sm + HISTC_OFF;
        uint32_t* scal  = sm + SCAL_OFF;
        uint32_t* tic   = sm + TIC_OFF;
        int nb1 = (N + 255) / 256;
        int nbu = nb1 < 1024 ? nb1 : 1024;
        int seglen = (N + NSEG - 1) / NSEG;
        float stride = 1024.0f / (float)(r - 1);

        int last = (s == 4);
        float* stage_out = (last && fused8) ? out : nxt;
        int nb = (last && fused8) ? 8 : 1;
        int bstride = (last && fused8) ? NMAXPIX : 0;

        k_upkey<<<dim3(nbu), dim3(256), 0, stream>>>(cur, rp, stage_out, r, nb, bstride, keys, histA);
        k_histmid<<<dim3(512), dim3(256), 0, stream>>>(keys, N, histA, scal, 1, npt, 0, 0,
                                                       0, 21, 10, 0x7FFu, histB, 2048);
        k_histmid<<<dim3(512), dim3(256), 0, stream>>>(keys, N, histB, scal, 0, 0u, 0, 11,
                                                       2, 10, 0, 0x3FFu, histC, 1024);
        k_segcnt<<<dim3(NSEG / 4), dim3(256), 0, stream>>>(keys, N, seglen, histC, scal, tic);
        k_seleval<<<dim3(NSEG / 4), dim3(256), 0, stream>>>(keys, N, seglen, scal, tic, r, stride,
                                                            stage_out, nb, bstride, w1, b1, w2, b2);
        if (!(last && fused8)) { float* tmp = cur; cur = nxt; nxt = tmp; }
    }
    if (!fused8) {
        // scratch lived in d_out; final grid at cur (= buf0 = d_out offset 0)
        k_bcast<<<dim3(((NMAXPIX + 3) / 4 + 255) / 256), dim3(256), 0, stream>>>(cur, out, NMAXPIX);
    }
}

// Round 13
// 244.288 us; speedup vs baseline: 1.5173x; 1.5173x over previous
//
#include <hip/hip_runtime.h>
#include <stdint.h>

#define HID 256
#define NMAXPIX (1025 * 1025)
#define NREP 8     // histogram replicas, replica-major: hist[rep*NB + bin]
#define NSEG 2048  // selection segments (one wave each; 512 blocks)
#define SELMAX 2112

// per-stage small-buffer layout (u32 units)
#define HISTA_OFF 0          // 8 x 2048
#define HISTB_OFF 16384      // 8 x 2048
#define HISTC_OFF 32768      // 8 x 1024
#define SCAL_OFF  40960      // [0]=pfx1 [1]=rem1 [2]=pfx2 [3]=rem2 [4]=K [5]=t (pad 64)
#define TIC_OFF   41024      // 2048
#define STAGE_U32 43072

// ---------------- MLP eval (single point), float4 LDS weight reads ----------------
__device__ __forceinline__ float mlp_eval4(float wx, float wy,
                                           const float4* __restrict__ w1x,
                                           const float4* __restrict__ w1y,
                                           const float4* __restrict__ vb1,
                                           const float4* __restrict__ vw2, float b2v) {
    const float C0 = (float)(0.5 / 1025.0);
    float px = (wx / 1025.0f + C0) * 2.0f - 1.0f;
    float py = (wy / 1025.0f + C0) * 2.0f - 1.0f;
    float a0 = 0.f, a1 = 0.f, a2 = 0.f, a3 = 0.f;
#pragma unroll 8
    for (int q = 0; q < HID / 4; ++q) {
        float4 a = w1x[q], b = w1y[q], c = vb1[q], d = vw2[q];
        float h0 = px * a.x + py * b.x + c.x;
        float h1 = px * a.y + py * b.y + c.y;
        float h2 = px * a.z + py * b.z + c.z;
        float h3 = px * a.w + py * b.w + c.w;
        h0 = h0 > 0.f ? h0 : 0.f;
        h1 = h1 > 0.f ? h1 : 0.f;
        h2 = h2 > 0.f ? h2 : 0.f;
        h3 = h3 > 0.f ? h3 : 0.f;
        a0 += h0 * d.x;
        a1 += h1 * d.y;
        a2 += h2 * d.z;
        a3 += h3 * d.w;
    }
    float x = ((a0 + a1) + (a2 + a3)) + b2v;
    float r;
    if (x >= 0.f) { r = 1.0f / (1.0f + expf(-x)); }
    else { float e = expf(x); r = e / (1.0f + e); }
    return r;
}

// ---------------- block exclusive scan helper (256 threads) ----------------
__device__ __forceinline__ uint32_t block_exscan_256(uint32_t v, volatile uint32_t* lds4) {
    int lane = threadIdx.x & 63, w = threadIdx.x >> 6;
    uint32_t inc = v;
#pragma unroll
    for (int d = 1; d < 64; d <<= 1) {
        uint32_t o = (uint32_t)__shfl_up((int)inc, d, 64);
        if (lane >= d) inc += o;
    }
    if (lane == 63) lds4[w] = inc;
    __syncthreads();
    uint32_t woff = 0;
    for (int i = 0; i < w; ++i) woff += lds4[i];
    return woff + inc - v;
}

// ---------------- redundant per-block radix scan of a replicated histogram ----------------
// hist built by the PREVIOUS dispatch (implicit barrier). Every block computes the same result.
__device__ void scan_dev(const uint32_t* __restrict__ hist, int NB,
                         uint32_t rem_in, uint32_t prefix_in, int shift,
                         uint32_t* outp, uint32_t* outr,
                         volatile uint32_t* lds4, volatile uint32_t* ldspair) {
    int tid = threadIdx.x;
    int C = NB >> 8;                 // 8 (NB=2048) or 4 (NB=1024)
    int b0 = NB - (tid + 1) * C;     // thread 0 owns top bins
    uint32_t cnts[8];
#pragma unroll
    for (int k = 0; k < 8; ++k) cnts[k] = 0;
    for (int rep = 0; rep < NREP; ++rep) {
        const uint4* p = (const uint4*)(hist + (size_t)rep * NB + b0);
#pragma unroll
        for (int g = 0; g < 2; ++g) {
            if (g * 4 < C) {
                uint4 v = p[g];
                cnts[g * 4 + 0] += v.x;
                cnts[g * 4 + 1] += v.y;
                cnts[g * 4 + 2] += v.z;
                cnts[g * 4 + 3] += v.w;
            }
        }
    }
    uint32_t ssum = 0;
    for (int k = 0; k < C; ++k) ssum += cnts[k];
    uint32_t excl = block_exscan_256(ssum, lds4);
    uint32_t run = excl;
    for (int k = 0; k < C; ++k) {
        uint32_t c = cnts[C - 1 - k];   // descending bin order within thread
        if (rem_in > run && rem_in <= run + c) {
            ldspair[0] = (prefix_in << shift) | (uint32_t)(b0 + C - 1 - k);
            ldspair[1] = rem_in - run;
        }
        run += c;
    }
    __syncthreads();
    *outp = ldspair[0];
    *outr = ldspair[1];
}

// ---------------- eval0 + zero all per-stage buffers (replaces memset dispatch) ----------------
__global__ __launch_bounds__(256) void k_eval0z(const float* __restrict__ w1, const float* __restrict__ b1,
                                                const float* __restrict__ w2, const float* __restrict__ b2,
                                                float* __restrict__ occ, uint32_t* __restrict__ zbuf, int zcount) {
    __shared__ alignas(16) float sw1[2 * HID];
    __shared__ alignas(16) float sb1[HID];
    __shared__ alignas(16) float sw2[HID];
    int tid = threadIdx.x;
    for (int i = tid; i < 2 * HID; i += 256) sw1[i] = w1[i];
    sb1[tid] = b1[tid];
    sw2[tid] = w2[tid];
    __syncthreads();
    int gtid = blockIdx.x * 256 + tid;
    int nthreads = gridDim.x * 256;
    for (int i = gtid; i < zcount; i += nthreads) zbuf[i] = 0;
    for (int n = gtid; n < 65 * 65; n += nthreads) {
        int i = n / 65, j = n % 65;
        occ[n] = mlp_eval4(16.0f * (float)j, 16.0f * (float)i,
                           (const float4*)sw1, (const float4*)(sw1 + HID),
                           (const float4*)sb1, (const float4*)sw2, b2[0]);
    }
}

// ---------------- upsample 2x + key + msb-11 hist (grid-stride; optional 8-batch write) ----------------
__global__ __launch_bounds__(256) void k_upkey(const float* __restrict__ in, int rp,
                                               float* __restrict__ outg, int r, int nb, int bstride,
                                               uint32_t* __restrict__ keys,
                                               uint32_t* __restrict__ histA) {
    __shared__ uint32_t hist[2048];
    int tid = threadIdx.x;
    for (int k = tid; k < 2048; k += 256) hist[k] = 0;
    __syncthreads();
    int N = r * r;
    int lane = tid & 63;
    int gstride = gridDim.x * 256;
    for (int n0 = blockIdx.x * 256; n0 < N; n0 += gstride) {
        int n = n0 + tid;
        bool act = n < N;
        uint32_t key = 0;
        if (act) {
            int i = n / r, j = n % r;
            int i2 = i >> 1, j2 = j >> 1;
            float v;
            if ((i & 1) == 0) {
                if ((j & 1) == 0) {
                    v = in[i2 * rp + j2];
                } else {
                    float a = in[i2 * rp + j2], b = in[i2 * rp + j2 + 1];
                    v = a * 0.5f + b * 0.5f;
                }
            } else {
                if ((j & 1) == 0) {
                    float a = in[i2 * rp + j2], b = in[(i2 + 1) * rp + j2];
                    v = a * 0.5f + b * 0.5f;
                } else {
                    float a = in[i2 * rp + j2],      c = in[i2 * rp + j2 + 1];
                    float b = in[(i2 + 1) * rp + j2], d = in[(i2 + 1) * rp + j2 + 1];
                    float t1 = a * 0.5f + b * 0.5f;
                    float t2 = c * 0.5f + d * 0.5f;
                    v = t1 * 0.5f + t2 * 0.5f;
                }
            }
            for (int k = 0; k < nb; ++k) outg[(size_t)k * bstride + n] = v;
            float unc = -fabsf(v - 0.5f);
            uint32_t u = __float_as_uint(unc);
            key = (u & 0x80000000u) ? ~u : (u | 0x80000000u);
            keys[n] = key;
        }
        uint32_t bin = key >> 21;
        unsigned long long m = __ballot(act);
        if (m) {
            int leader = __ffsll(m) - 1;
            uint32_t lbin = (uint32_t)__shfl((int)bin, leader, 64);
            unsigned long long smk = __ballot(act && bin == lbin);
            if (smk == m) {
                if (lane == leader) atomicAdd(&hist[lbin], (uint32_t)__popcll(m));
            } else if (act) {
                atomicAdd(&hist[bin], 1u);
            }
        }
    }
    __syncthreads();
    uint32_t* myrep = histA + (size_t)(blockIdx.x & (NREP - 1)) * 2048;
    for (int k = tid; k < 2048; k += 256) {
        uint32_t c = hist[k];
        if (c) atomicAdd(&myrep[k], c);
    }
}

// ---------------- filtered histogram pass (scan of prev hist fused in, per block) ----------------
__global__ __launch_bounds__(256) void k_histmid(const uint32_t* __restrict__ keys, int N,
                                                 const uint32_t* __restrict__ prevHist,
                                                 uint32_t* __restrict__ scal,
                                                 int useNpt, uint32_t npt, int scalInIdx, int shift,
                                                 int scalOutIdx,
                                                 int fshift, int bshift, uint32_t bmask,
                                                 uint32_t* __restrict__ outHist, int NBout) {
    __shared__ uint32_t lh[2048];
    __shared__ uint32_t lds4[4];
    __shared__ uint32_t ldspair[2];
    int tid = threadIdx.x, lane = tid & 63;
    uint32_t rem_in = useNpt ? npt : scal[scalInIdx + 1];
    uint32_t pfx_in = useNpt ? 0u  : scal[scalInIdx];
    uint32_t pfx, rem;
    scan_dev(prevHist, 2048, rem_in, pfx_in, shift, &pfx, &rem, lds4, ldspair);
    if (blockIdx.x == 0 && tid == 0) { scal[scalOutIdx] = pfx; scal[scalOutIdx + 1] = rem; }
    for (int k = tid; k < 2048; k += 256) lh[k] = 0;
    __syncthreads();
    int gstride = gridDim.x * 256;
    for (int base = blockIdx.x * 256; base < N; base += gstride) {
        int n = base + tid;
        bool inb = n < N;
        uint32_t key = inb ? keys[n] : 0u;
        bool flt = inb && ((key >> fshift) == pfx);
        uint32_t bin = (key >> bshift) & bmask;
        unsigned long long m = __ballot(flt);
        if (m) {
            int leader = __ffsll(m) - 1;
            uint32_t lbin = (uint32_t)__shfl((int)bin, leader, 64);
            unsigned long long smk = __ballot(flt && bin == lbin);
            if (smk == m) {
                if (lane == leader) atomicAdd(&lh[lbin], (uint32_t)__popcll(m));
            } else if (flt) {
                atomicAdd(&lh[bin], 1u);
            }
        }
    }
    __syncthreads();
    uint32_t* myrep = outHist + (size_t)(blockIdx.x & (NREP - 1)) * NBout;
    for (int k = tid; k < NBout; k += 256) {
        uint32_t c = lh[k];
        if (c) atomicAdd(&myrep[k], c);
    }
}

// ---------------- final scan (K,t) fused + per-segment tie counts ----------------
__global__ __launch_bounds__(256) void k_segcnt(const uint32_t* __restrict__ keys, int N, int seglen,
                                                const uint32_t* __restrict__ histC,
                                                uint32_t* __restrict__ scal,
                                                uint32_t* __restrict__ tic) {
    __shared__ uint32_t lds4[4];
    __shared__ uint32_t ldspair[2];
    int tid = threadIdx.x, lane = tid & 63;
    uint32_t rem2 = scal[3], pfx2 = scal[2];
    uint32_t K, t;
    scan_dev(histC, 1024, rem2, pfx2, 10, &K, &t, lds4, ldspair);
    if (blockIdx.x == 0 && tid == 0) { scal[4] = K; scal[5] = t; }
    int wv = blockIdx.x * 4 + (tid >> 6);
    int s0 = wv * seglen;
    int s1 = s0 + seglen; if (s1 > N) s1 = N;
    uint32_t tcnt = 0;
    for (int base = s0; base < s1; base += 64) {
        int n = base + lane;
        if (n < s1) tcnt += (keys[n] == K) ? 1u : 0u;
    }
#pragma unroll
    for (int d = 32; d; d >>= 1) tcnt += (uint32_t)__shfl_down((int)tcnt, d, 64);
    if (lane == 0) tic[wv] = tcnt;
}

// ---------------- fused select (exact top-k, index-ascending ties) + LDS compact + dense eval ----------------
__global__ __launch_bounds__(256) void k_seleval(const uint32_t* __restrict__ keys, int N, int seglen,
                                                 const uint32_t* __restrict__ scal,
                                                 const uint32_t* __restrict__ tic,
                                                 int r, float stride,
                                                 float* __restrict__ occ, int nb, int bstride,
                                                 const float* __restrict__ w1, const float* __restrict__ b1,
                                                 const float* __restrict__ w2, const float* __restrict__ b2) {
    __shared__ alignas(16) float sw1[2 * HID];
    __shared__ alignas(16) float sb1[HID];
    __shared__ alignas(16) float sw2[HID];
    __shared__ uint32_t selcnt;
    __shared__ uint32_t selidx[SELMAX];
    int tid = threadIdx.x, lane = tid & 63;
    for (int i = tid; i < 2 * HID; i += 256) sw1[i] = w1[i];
    sb1[tid] = b1[tid];
    sw2[tid] = w2[tid];
    if (tid == 0) selcnt = 0;
    __syncthreads();
    uint32_t K = scal[4], t = scal[5];

    // per-wave exclusive tie prefix over segments [0, wv)
    int wv = blockIdx.x * 4 + (tid >> 6);
    uint32_t tp = 0;
    for (int i = lane; i < wv; i += 64) tp += tic[i];
#pragma unroll
    for (int d = 32; d; d >>= 1) tp += (uint32_t)__shfl_down((int)tp, d, 64);
    tp = (uint32_t)__shfl((int)tp, 0, 64);

    uint32_t tie_run = tp;
    int s0 = wv * seglen;
    int s1 = s0 + seglen; if (s1 > N) s1 = N;
    unsigned long long lowmask = (lane == 63) ? ~0ull >> 1 : ((1ull << lane) - 1ull);
    for (int base = s0; base < s1; base += 64) {
        int n = base + lane;
        bool inb = n < s1;
        uint32_t key = inb ? keys[n] : 0u;
        bool gt = inb && (key > K);
        bool tie = inb && (key == K);
        unsigned long long tm = __ballot(tie);
        uint32_t trank = tie_run + (uint32_t)__popcll(tm & lowmask);
        bool sel = gt || (tie && trank < t);
        unsigned long long smk = __ballot(sel);
        if (smk) {
            int leader = __ffsll(smk) - 1;
            uint32_t wbase = 0;
            if (lane == leader) wbase = atomicAdd(&selcnt, (uint32_t)__popcll(smk));
            wbase = (uint32_t)__shfl((int)wbase, leader, 64);
            if (sel) selidx[wbase + (uint32_t)__popcll(smk & lowmask)] = (uint32_t)n;
        }
        tie_run += (uint32_t)__popcll(tm);
    }
    __syncthreads();

    // dense eval: 2 points per thread per iteration (shared weight reads), no divergence
    uint32_t cnt = selcnt;
    float vb2 = b2[0];
    const float4* w1x = (const float4*)sw1;
    const float4* w1y = (const float4*)(sw1 + HID);
    const float4* vb1 = (const float4*)sb1;
    const float4* vw2 = (const float4*)sw2;
    const float C0 = (float)(0.5 / 1025.0);
    for (uint32_t bb = 0; bb < cnt; bb += 512) {
        uint32_t i0 = bb + tid, i1 = bb + tid + 256;
        bool v0 = i0 < cnt, v1 = i1 < cnt;
        int nA = v0 ? (int)selidx[i0] : 0;
        int nB = v1 ? (int)selidx[i1] : 0;
        int iA = nA / r, jA = nA % r;
        int iB = nB / r, jB = nB % r;
        float pxA = ((stride * (float)jA) / 1025.0f + C0) * 2.0f - 1.0f;
        float pyA = ((stride * (float)iA) / 1025.0f + C0) * 2.0f - 1.0f;
        float pxB = ((stride * (float)jB) / 1025.0f + C0) * 2.0f - 1.0f;
        float pyB = ((stride * (float)iB) / 1025.0f + C0) * 2.0f - 1.0f;
        float4 A0 = {0, 0, 0, 0}, A1 = {0, 0, 0, 0};
#pragma unroll 4
        for (int q = 0; q < HID / 4; ++q) {
            float4 a = w1x[q], b = w1y[q], c = vb1[q], d = vw2[q];
            {
                float h0 = pxA * a.x + pyA * b.x + c.x;
                float h1 = pxA * a.y + pyA * b.y + c.y;
                float h2 = pxA * a.z + pyA * b.z + c.z;
                float h3 = pxA * a.w + pyA * b.w + c.w;
                h0 = h0 > 0.f ? h0 : 0.f;
                h1 = h1 > 0.f ? h1 : 0.f;
                h2 = h2 > 0.f ? h2 : 0.f;
                h3 = h3 > 0.f ? h3 : 0.f;
                A0.x += h0 * d.x; A0.y += h1 * d.y;
                A0.z += h2 * d.z; A0.w += h3 * d.w;
            }
            {
                float h0 = pxB * a.x + pyB * b.x + c.x;
                float h1 = pxB * a.y + pyB * b.y + c.y;
                float h2 = pxB * a.z + pyB * b.z + c.z;
                float h3 = pxB * a.w + pyB * b.w + c.w;
                h0 = h0 > 0.f ? h0 : 0.f;
                h1 = h1 > 0.f ? h1 : 0.f;
                h2 = h2 > 0.f ? h2 : 0.f;
                h3 = h3 > 0.f ? h3 : 0.f;
                A1.x += h0 * d.x; A1.y += h1 * d.y;
                A1.z += h2 * d.z; A1.w += h3 * d.w;
            }
        }
        if (v0) {
            float x = ((A0.x + A0.y) + (A0.z + A0.w)) + vb2;
            float rr;
            if (x >= 0.f) { rr = 1.0f / (1.0f + expf(-x)); }
            else { float e = expf(x); rr = e / (1.0f + e); }
            for (int k = 0; k < nb; ++k) occ[(size_t)k * bstride + nA] = rr;
        }
        if (v1) {
            float x = ((A1.x + A1.y) + (A1.z + A1.w)) + vb2;
            float rr;
            if (x >= 0.f) { rr = 1.0f / (1.0f + expf(-x)); }
            else { float e = expf(x); rr = e / (1.0f + e); }
            for (int k = 0; k < nb; ++k) occ[(size_t)k * bstride + nB] = rr;
        }
    }
}

// ---------------- fallback-only broadcast (used when d_ws is too small) ----------------
__global__ __launch_bounds__(256) void k_bcast(const float* __restrict__ src, float* __restrict__ dst, int N) {
    int q = blockIdx.x * 256 + threadIdx.x;
    int n = q * 4;
    if (n + 3 < N) {
        float4 v = *(const float4*)(src + n);
#pragma unroll
        for (int k = 0; k < 8; ++k) *(float4*)(dst + (size_t)k * N + n) = v;
    } else if (n < N) {
        for (int m = n; m < N; ++m) {
            float v = src[m];
#pragma unroll
            for (int k = 0; k < 8; ++k) dst[(size_t)k * N + m] = v;
        }
    }
}

extern "C" void kernel_launch(void* const* d_in, const int* in_sizes, int n_in,
                              void* d_out, int out_size, void* d_ws, size_t ws_size,
                              hipStream_t stream) {
    const float* w1 = (const float*)d_in[0];
    const float* b1 = (const float*)d_in[1];
    const float* w2 = (const float*)d_in[2];
    const float* b2 = (const float*)d_in[3];
    float* out = (float*)d_out;

    const size_t A = (((size_t)NMAXPIX * 4) + 255) & ~(size_t)255;  // one grid buffer
    const size_t SMALL_BYTES = (size_t)4 * STAGE_U32 * 4;            // 4 stages (~690 KB)
    const size_t need = 3 * A + SMALL_BYTES;

    int fused8 = (ws_size >= need);  // stage-4 writes all 8 batches directly only when ws holds scratch
    char* base = fused8 ? (char*)d_ws : (char*)d_out;
    float* buf0 = (float*)(base);
    float* buf1 = (float*)(base + A);
    uint32_t* keys = (uint32_t*)(base + 2 * A);
    uint32_t* smallb = (uint32_t*)(base + 3 * A);

    // dispatch 1: zero all stage buffers + dense 65x65 eval
    k_eval0z<<<dim3(512), dim3(256), 0, stream>>>(w1, b1, w2, b2, buf0, smallb, 4 * STAGE_U32);

    const int resA[5] = {65, 129, 257, 513, 1025};
    const int nptA[5] = {0, 4096, 16384, 65536, 262144};
    float* cur = buf0;
    float* nxt = buf1;
    for (int s = 1; s < 5; ++s) {
        int rp = resA[s - 1], r = resA[s];
        int N = r * r;
        uint32_t npt = (uint32_t)nptA[s];
        uint32_t* sm    = smallb + (size_t)(s - 1) * STAGE_U32;
        uint32_t* histA = sm + HISTA_OFF;
        uint32_t* histB = sm + HISTB_OFF;
        uint32_t* histC = sm + HISTC_OFF;
        uint32_t* scal  = sm + SCAL_OFF;
        uint32_t* tic   = sm + TIC_OFF;
        int nb1 = (N + 255) / 256;
        int nbu = nb1 < 1024 ? nb1 : 1024;
        int seglen = (N + NSEG - 1) / NSEG;
        float stride = 1024.0f / (float)(r - 1);

        int last = (s == 4);
        float* stage_out = (last && fused8) ? out : nxt;
        int nb = (last && fused8) ? 8 : 1;
        int bstride = (last && fused8) ? NMAXPIX : 0;

        k_upkey<<<dim3(nbu), dim3(256), 0, stream>>>(cur, rp, stage_out, r, nb, bstride, keys, histA);
        k_histmid<<<dim3(512), dim3(256), 0, stream>>>(keys, N, histA, scal, 1, npt, 0, 0,
                                                       0, 21, 10, 0x7FFu, histB, 2048);
        k_histmid<<<dim3(512), dim3(256), 0, stream>>>(keys, N, histB, scal, 0, 0u, 0, 11,
                                                       2, 10, 0, 0x3FFu, histC, 1024);
        k_segcnt<<<dim3(NSEG / 4), dim3(256), 0, stream>>>(keys, N, seglen, histC, scal, tic);
        k_seleval<<<dim3(NSEG / 4), dim3(256), 0, stream>>>(keys, N, seglen, scal, tic, r, stride,
                                                            stage_out, nb, bstride, w1, b1, w2, b2);
        if (!(last && fused8)) { float* tmp = cur; cur = nxt; nxt = tmp; }
    }
    if (!fused8) {
        // fallback: scratch lived in d_out; final grid is at cur (= buf0 offset 0)
        k_bcast<<<dim3(((NMAXPIX + 3) / 4 + 255) / 256), dim3(256), 0, stream>>>(cur, out, NMAXPIX);
    }
}